// Round 9
// baseline (2695.980 us; speedup 1.0000x reference)
//
#include <hip/hip_runtime.h>
#include <stdint.h>

#define HID 2048
#define ITR 5632
#define NE 8
#define TT 8192
#define BM 128
#define BN 128
#define BK 64
#define MT1 64          // max m-tiles per expert (8192/128)
#define NT1 44          // ITR/BN
#define NT2 16          // HID/BN
#define WBLK 45056      // (NE*ITR*HID)/2048 = fp32->bf16 chunks per weight tensor

typedef __attribute__((ext_vector_type(4))) float f4;
typedef __attribute__((ext_vector_type(8))) short s8v;      // 8 bf16 (MFMA frag)
typedef __attribute__((ext_vector_type(4))) float acc4;     // MFMA accum
typedef __attribute__((ext_vector_type(4))) unsigned short u4v;
typedef __attribute__((ext_vector_type(8))) unsigned short u8v;

__device__ __forceinline__ unsigned short f2bf(float f) {
    union { float f; uint32_t u; } v; v.f = f;
    uint32_t u = v.u;
    return (unsigned short)((u + 0x7FFFu + ((u >> 16) & 1u)) >> 16);
}

__device__ __forceinline__ void gload16(const unsigned short* g, unsigned short* l) {
    __builtin_amdgcn_global_load_lds(
        (const __attribute__((address_space(1))) unsigned int*)g,
        (__attribute__((address_space(3))) unsigned int*)l, 16, 0, 0);
}

#define MFMA16(a, b, c) __builtin_amdgcn_mfma_f32_16x16x32_bf16(a, b, c, 0, 0, 0)

// ---------- fused: x fp32 -> bf16 AND router top-2 ----------
__global__ __launch_bounds__(256) void k_xrt(const float* __restrict__ x,
                                             const float* __restrict__ rw,
                                             const float* __restrict__ rb,
                                             unsigned short* __restrict__ xb,
                                             int* __restrict__ cnt,
                                             int* __restrict__ tokL,
                                             int* __restrict__ slotL,
                                             float* __restrict__ gateL) {
    int lane = threadIdx.x & 63;
    int wv = threadIdx.x >> 6;
    int t = blockIdx.x * 4 + wv;
    const float* xr = x + (size_t)t * HID;
    unsigned short* xo = xb + (size_t)t * HID;
    float acc[NE];
    #pragma unroll
    for (int e = 0; e < NE; ++e) acc[e] = 0.f;
    #pragma unroll
    for (int i = 0; i < 8; ++i) {
        f4 xv = *(const f4*)(xr + i * 256 + lane * 4);
        u4v o = { f2bf(xv.x), f2bf(xv.y), f2bf(xv.z), f2bf(xv.w) };
        *(u4v*)(xo + i * 256 + lane * 4) = o;
        #pragma unroll
        for (int e = 0; e < NE; ++e) {
            f4 wv4 = *(const f4*)(rw + e * HID + i * 256 + lane * 4);
            acc[e] += xv.x * wv4.x + xv.y * wv4.y + xv.z * wv4.z + xv.w * wv4.w;
        }
    }
    #pragma unroll
    for (int off = 32; off; off >>= 1)
        #pragma unroll
        for (int e = 0; e < NE; ++e) acc[e] += __shfl_xor(acc[e], off, 64);
    if (lane == 0) {
        float lg[NE];
        #pragma unroll
        for (int e = 0; e < NE; ++e) lg[e] = acc[e] + rb[e];
        int i1 = 0;
        #pragma unroll
        for (int e = 1; e < NE; ++e) if (lg[e] > lg[i1]) i1 = e;   // earliest max (jax tie rule)
        int i2 = -1;
        #pragma unroll
        for (int e = 0; e < NE; ++e) {
            if (e == i1) continue;
            if (i2 < 0 || lg[e] > lg[i2]) i2 = e;
        }
        float ex = __expf(lg[i2] - lg[i1]);   // <= 1
        float w1 = 1.f / (1.f + ex);
        float w2 = ex / (1.f + ex);
        int p = atomicAdd(&cnt[i1], 1);
        tokL[i1 * TT + p] = t; slotL[i1 * TT + p] = t * 2;     gateL[i1 * TT + p] = w1;
        p = atomicAdd(&cnt[i2], 1);
        tokL[i2 * TT + p] = t; slotL[i2 * TT + p] = t * 2 + 1; gateL[i2 * TT + p] = w2;
    }
}

// ---------- Wg + Wu fp32 -> bf16, one launch (Wd handled inside gemm1) ----------
__global__ __launch_bounds__(256) void k_cvtGU(const float* __restrict__ a,
                                               const float* __restrict__ b,
                                               unsigned short* __restrict__ oa,
                                               unsigned short* __restrict__ ob) {
    int bb = blockIdx.x;
    const float* s; unsigned short* d;
    if (bb < WBLK) { s = a; d = oa; }
    else           { s = b; d = ob; bb -= WBLK; }
    size_t i = ((size_t)bb * 256 + threadIdx.x) * 8;
    f4 va = *(const f4*)(s + i);
    f4 vb = *(const f4*)(s + i + 4);
    u8v o;
    o[0]=f2bf(va.x); o[1]=f2bf(va.y); o[2]=f2bf(va.z); o[3]=f2bf(va.w);
    o[4]=f2bf(vb.x); o[5]=f2bf(vb.y); o[6]=f2bf(vb.z); o[7]=f2bf(vb.w);
    *(u8v*)(d + i) = o;
}

// ============================================================================
// FAST PATH: bf16 weights, global_load_lds staging, 128x128 tile, BK=64,
// XOR swizzle ^((row&7)<<4). Grid order mt-FASTEST (consecutive blocks share
// the weight n-slice; per-expert A slice stays L2-resident).
// Idle gemm1 blocks (mt beyond this expert's token range) convert Wd fp32->
// bf16 in deterministic strided chunks, overlapping conversion with compute.
// ============================================================================

// ---------- GEMM1: Hb[slot] = silu(X Wg^T) * (X Wu^T) + Wd conversion ----------
__global__ __launch_bounds__(256, 2) void k_gemm1b(const unsigned short* __restrict__ xb,
                                                   const unsigned short* __restrict__ WgB,
                                                   const unsigned short* __restrict__ WuB,
                                                   const float* __restrict__ Wd,
                                                   unsigned short* __restrict__ WdB,
                                                   const int* __restrict__ cnt,
                                                   const int* __restrict__ tokL,
                                                   const int* __restrict__ slotL,
                                                   unsigned short* __restrict__ Hb) {
    int bx = blockIdx.x;
    int e = bx / (MT1 * NT1);
    int r = bx % (MT1 * NT1);
    int nt = r / MT1, mt = r % MT1;       // mt fastest
    int M = cnt[e];
    int m0 = mt * BM;
    int tid = threadIdx.x;

    if (m0 >= M) {
        // -------- idle block: Wd fp32 -> bf16 conversion duty --------
        // Deterministic: index this block among ALL idle blocks (cnt[] is
        // final before this kernel launches), stride over WBLK chunks.
        int used = (M + BM - 1) / BM;                     // this expert's used mt
        int idlePre = 0, nIdle = 0;
        #pragma unroll
        for (int ee = 0; ee < NE; ++ee) {
            int ue = (cnt[ee] + BM - 1) / BM;
            if (ue > MT1) ue = MT1;
            int ie = MT1 - ue;
            if (ee < e) idlePre += ie;
            nIdle += ie;
        }
        int idleE = MT1 - used;                           // this expert's idle mt
        int myIdx = idlePre * NT1 + nt * idleE + (mt - used);
        int stride = nIdle * NT1;
        for (int c = myIdx; c < WBLK; c += stride) {
            size_t i = (size_t)c * 2048 + tid * 8;
            f4 va = *(const f4*)(Wd + i);
            f4 vb = *(const f4*)(Wd + i + 4);
            u8v o;
            o[0]=f2bf(va.x); o[1]=f2bf(va.y); o[2]=f2bf(va.z); o[3]=f2bf(va.w);
            o[4]=f2bf(vb.x); o[5]=f2bf(vb.y); o[6]=f2bf(vb.z); o[7]=f2bf(vb.w);
            *(u8v*)(WdB + i) = o;
        }
        return;
    }
    int n0 = nt * BN;

    __shared__ __align__(16) unsigned short lA[BM * BK];
    __shared__ __align__(16) unsigned short lBg[BN * BK];
    __shared__ __align__(16) unsigned short lBu[BN * BK];
    __shared__ int sTok[BM];
    __shared__ int sSlot[BM];

    if (tid < BM) {
        int m = m0 + tid;
        int mc = m < M ? m : M - 1;
        sTok[tid] = tokL[e * TT + mc];
        sSlot[tid] = slotL[e * TT + mc];
    }
    __syncthreads();

    int wv = tid >> 6, lane = tid & 63;
    int subrow = lane >> 3;                      // 0..7 = row within 8-row chunk
    int colE = ((lane & 7) ^ subrow) * 8;        // inverse-swizzled source col (elems)

    const unsigned short* aSrc[4];
    const unsigned short* gSrc[4];
    const unsigned short* uSrc[4];
    #pragma unroll
    for (int i = 0; i < 4; ++i) {
        int row = (i * 4 + wv) * 8 + subrow;
        aSrc[i] = xb + (size_t)sTok[row] * HID + colE;
        gSrc[i] = WgB + ((size_t)e * ITR + n0 + row) * HID + colE;
        uSrc[i] = WuB + ((size_t)e * ITR + n0 + row) * HID + colE;
    }

    int wm = (wv >> 1) * 64, wn = (wv & 1) * 64;
    int lr = lane & 15, lk = (lane >> 4) * 8;

    acc4 zero4 = {0.f, 0.f, 0.f, 0.f};
    acc4 ag[4][4], au[4][4];
    #pragma unroll
    for (int mi = 0; mi < 4; ++mi)
        #pragma unroll
        for (int ni = 0; ni < 4; ++ni) { ag[mi][ni] = zero4; au[mi][ni] = zero4; }

    for (int k0 = 0; k0 < HID; k0 += BK) {
        if (k0) __syncthreads();
        #pragma unroll
        for (int i = 0; i < 4; ++i) {
            gload16(aSrc[i] + k0, lA  + (i * 4 + wv) * 512);
            gload16(gSrc[i] + k0, lBg + (i * 4 + wv) * 512);
            gload16(uSrc[i] + k0, lBu + (i * 4 + wv) * 512);
        }
        __syncthreads();
        #pragma unroll
        for (int kk = 0; kk < BK; kk += 32) {
            s8v af[4], gf[4], uf[4];
            #pragma unroll
            for (int i = 0; i < 4; ++i) {
                int rowA = wm + i * 16 + lr;
                af[i] = *(const s8v*)((char*)lA + ((rowA * 128 + (kk + lk) * 2) ^ ((rowA & 7) << 4)));
                int rowB = wn + i * 16 + lr;
                int bb = (rowB * 128 + (kk + lk) * 2) ^ ((rowB & 7) << 4);
                gf[i] = *(const s8v*)((char*)lBg + bb);
                uf[i] = *(const s8v*)((char*)lBu + bb);
            }
            #pragma unroll
            for (int mi = 0; mi < 4; ++mi)
                #pragma unroll
                for (int ni = 0; ni < 4; ++ni) {
                    ag[mi][ni] = MFMA16(af[mi], gf[ni], ag[mi][ni]);
                    au[mi][ni] = MFMA16(af[mi], uf[ni], au[mi][ni]);
                }
        }
    }
    #pragma unroll
    for (int mi = 0; mi < 4; ++mi) {
        #pragma unroll
        for (int j2 = 0; j2 < 4; ++j2) {
            int m = wm + mi * 16 + (lane >> 4) * 4 + j2;
            if (m0 + m < M) {
                size_t rowOff = (size_t)sSlot[m] * ITR + n0 + wn + lr;
                #pragma unroll
                for (int ni = 0; ni < 4; ++ni) {
                    float g = ag[mi][ni][j2], u = au[mi][ni][j2];
                    float h = g * (1.f / (1.f + __expf(-g))) * u;
                    Hb[rowOff + ni * 16] = f2bf(h);
                }
            }
        }
    }
}

// ---------- GEMM2: out[t] += gate * (Hb[slot] Wd^T) ----------
__global__ __launch_bounds__(256, 3) void k_gemm2b(const unsigned short* __restrict__ Hb,
                                                   const unsigned short* __restrict__ WdB,
                                                   const int* __restrict__ cnt,
                                                   const int* __restrict__ tokL,
                                                   const int* __restrict__ slotL,
                                                   const float* __restrict__ gateL,
                                                   float* __restrict__ out) {
    int bx = blockIdx.x;
    int e = bx / (MT1 * NT2);
    int r = bx % (MT1 * NT2);
    int nt = r / MT1, mt = r % MT1;       // mt fastest
    int M = cnt[e];
    int m0 = mt * BM;
    if (m0 >= M) return;
    int n0 = nt * BN;

    __shared__ __align__(16) unsigned short lA[BM * BK];
    __shared__ __align__(16) unsigned short lB[BN * BK];
    __shared__ int sTok[BM];
    __shared__ int sSlot[BM];
    __shared__ float sGate[BM];

    int tid = threadIdx.x;
    if (tid < BM) {
        int m = m0 + tid;
        int mc = m < M ? m : M - 1;
        sTok[tid] = tokL[e * TT + mc];
        sSlot[tid] = slotL[e * TT + mc];
        sGate[tid] = gateL[e * TT + mc];
    }
    __syncthreads();

    int wv = tid >> 6, lane = tid & 63;
    int subrow = lane >> 3;
    int colE = ((lane & 7) ^ subrow) * 8;

    const unsigned short* aSrc[4];
    const unsigned short* bSrc[4];
    #pragma unroll
    for (int i = 0; i < 4; ++i) {
        int row = (i * 4 + wv) * 8 + subrow;
        aSrc[i] = Hb + (size_t)sSlot[row] * ITR + colE;
        bSrc[i] = WdB + ((size_t)e * HID + n0 + row) * ITR + colE;
    }

    int wm = (wv >> 1) * 64, wn = (wv & 1) * 64;
    int lr = lane & 15, lk = (lane >> 4) * 8;

    acc4 zero4 = {0.f, 0.f, 0.f, 0.f};
    acc4 a4[4][4];
    #pragma unroll
    for (int mi = 0; mi < 4; ++mi)
        #pragma unroll
        for (int ni = 0; ni < 4; ++ni) a4[mi][ni] = zero4;

    for (int k0 = 0; k0 < ITR; k0 += BK) {
        if (k0) __syncthreads();
        #pragma unroll
        for (int i = 0; i < 4; ++i) {
            gload16(aSrc[i] + k0, lA + (i * 4 + wv) * 512);
            gload16(bSrc[i] + k0, lB + (i * 4 + wv) * 512);
        }
        __syncthreads();
        #pragma unroll
        for (int kk = 0; kk < BK; kk += 32) {
            s8v af[4], bf[4];
            #pragma unroll
            for (int i = 0; i < 4; ++i) {
                int rowA = wm + i * 16 + lr;
                af[i] = *(const s8v*)((char*)lA + ((rowA * 128 + (kk + lk) * 2) ^ ((rowA & 7) << 4)));
                int rowB = wn + i * 16 + lr;
                bf[i] = *(const s8v*)((char*)lB + ((rowB * 128 + (kk + lk) * 2) ^ ((rowB & 7) << 4)));
            }
            #pragma unroll
            for (int mi = 0; mi < 4; ++mi)
                #pragma unroll
                for (int ni = 0; ni < 4; ++ni)
                    a4[mi][ni] = MFMA16(af[mi], bf[ni], a4[mi][ni]);
        }
    }
    #pragma unroll
    for (int mi = 0; mi < 4; ++mi) {
        #pragma unroll
        for (int j2 = 0; j2 < 4; ++j2) {
            int m = wm + mi * 16 + (lane >> 4) * 4 + j2;
            if (m0 + m < M) {
                int t = sTok[m];
                float w = sGate[m];
                float* orow = out + (size_t)t * HID + n0 + wn + lr;
                #pragma unroll
                for (int ni = 0; ni < 4; ++ni)
                    atomicAdd(orow + ni * 16, w * a4[mi][ni][j2]);
            }
        }
    }
}

// ============================================================================
// FALLBACK PATH (fp32 weights staged in-kernel) — only if ws too small.
// ============================================================================

__global__ __launch_bounds__(256) void k_gemm1(const unsigned short* __restrict__ xb,
                                               const float* __restrict__ Wg,
                                               const float* __restrict__ Wu,
                                               const int* __restrict__ cnt,
                                               const int* __restrict__ tokL,
                                               const int* __restrict__ slotL,
                                               unsigned short* __restrict__ Hb) {
    int bx = blockIdx.x;
    int e = bx / (MT1 * NT1);
    int r = bx % (MT1 * NT1);
    int mt = r / NT1, nt = r % NT1;
    int M = cnt[e];
    int m0 = mt * BM;
    if (m0 >= M) return;
    int n0 = nt * BN;

    __shared__ __align__(16) unsigned short lA[BM * BK];
    __shared__ __align__(16) unsigned short lBg[BN * BK];
    __shared__ __align__(16) unsigned short lBu[BN * BK];
    __shared__ int sTok[BM];
    __shared__ int sSlot[BM];

    int tid = threadIdx.x;
    if (tid < BM) {
        int m = m0 + tid;
        int mc = m < M ? m : M - 1;
        sTok[tid] = tokL[e * TT + mc];
        sSlot[tid] = slotL[e * TT + mc];
    }
    __syncthreads();

    int ar = tid >> 3, ac = tid & 7;
    const unsigned short* aP[4];
    #pragma unroll
    for (int i = 0; i < 4; ++i)
        aP[i] = xb + (size_t)sTok[ar + 32 * i] * HID + ac * 8;

    int br = tid >> 4, bc = tid & 15;
    const float* gB = Wg + ((size_t)e * ITR + n0) * HID + bc * 4;
    const float* uB = Wu + ((size_t)e * ITR + n0) * HID + bc * 4;

    int wv = tid >> 6, lane = tid & 63;
    int wm = (wv >> 1) * 64, wn = (wv & 1) * 64;
    int lr = lane & 15, lk = (lane >> 4) * 8;

    acc4 zero4 = {0.f, 0.f, 0.f, 0.f};
    acc4 ag[4][4], au[4][4];
    #pragma unroll
    for (int mi = 0; mi < 4; ++mi)
        #pragma unroll
        for (int ni = 0; ni < 4; ++ni) { ag[mi][ni] = zero4; au[mi][ni] = zero4; }

    for (int k0 = 0; k0 < HID; k0 += BK) {
        if (k0) __syncthreads();
        #pragma unroll
        for (int i = 0; i < 4; ++i) {
            int row = ar + 32 * i;
            s8v v = *(const s8v*)(aP[i] + k0);
            int byt = (row * 128 + ac * 16) ^ ((row & 7) << 4);
            *(s8v*)((char*)lA + byt) = v;
        }
        #pragma unroll
        for (int i = 0; i < 8; ++i) {
            int row = br + 16 * i;
            f4 vg = *(const f4*)(gB + (size_t)row * HID + k0);
            f4 vu = *(const f4*)(uB + (size_t)row * HID + k0);
            u4v og = { f2bf(vg.x), f2bf(vg.y), f2bf(vg.z), f2bf(vg.w) };
            u4v ou = { f2bf(vu.x), f2bf(vu.y), f2bf(vu.z), f2bf(vu.w) };
            int byt = (row * 128 + bc * 8) ^ ((row & 7) << 4);
            *(u4v*)((char*)lBg + byt) = og;
            *(u4v*)((char*)lBu + byt) = ou;
        }
        __syncthreads();
        #pragma unroll
        for (int kk = 0; kk < BK; kk += 32) {
            s8v af[4], gf[4], uf[4];
            #pragma unroll
            for (int i = 0; i < 4; ++i) {
                int rowA = wm + i * 16 + lr;
                af[i] = *(const s8v*)((char*)lA + ((rowA * 128 + (kk + lk) * 2) ^ ((rowA & 7) << 4)));
                int rowB = wn + i * 16 + lr;
                int bb = (rowB * 128 + (kk + lk) * 2) ^ ((rowB & 7) << 4);
                gf[i] = *(const s8v*)((char*)lBg + bb);
                uf[i] = *(const s8v*)((char*)lBu + bb);
            }
            #pragma unroll
            for (int mi = 0; mi < 4; ++mi)
                #pragma unroll
                for (int ni = 0; ni < 4; ++ni) {
                    ag[mi][ni] = MFMA16(af[mi], gf[ni], ag[mi][ni]);
                    au[mi][ni] = MFMA16(af[mi], uf[ni], au[mi][ni]);
                }
        }
    }
    #pragma unroll
    for (int mi = 0; mi < 4; ++mi) {
        #pragma unroll
        for (int j = 0; j < 4; ++j) {
            int m = wm + mi * 16 + (lane >> 4) * 4 + j;
            if (m0 + m < M) {
                size_t rowOff = (size_t)sSlot[m] * ITR + n0 + wn + lr;
                #pragma unroll
                for (int ni = 0; ni < 4; ++ni) {
                    float g = ag[mi][ni][j], u = au[mi][ni][j];
                    float h = g * (1.f / (1.f + __expf(-g))) * u;
                    Hb[rowOff + ni * 16] = f2bf(h);
                }
            }
        }
    }
}

__global__ __launch_bounds__(256) void k_gemm2(const unsigned short* __restrict__ Hb,
                                               const float* __restrict__ Wd,
                                               const int* __restrict__ cnt,
                                               const int* __restrict__ tokL,
                                               const int* __restrict__ slotL,
                                               const float* __restrict__ gateL,
                                               float* __restrict__ out) {
    int bx = blockIdx.x;
    int e = bx / (MT1 * NT2);
    int r = bx % (MT1 * NT2);
    int mt = r / NT2, nt = r % NT2;
    int M = cnt[e];
    int m0 = mt * BM;
    if (m0 >= M) return;
    int n0 = nt * BN;

    __shared__ __align__(16) unsigned short lA[BM * BK];
    __shared__ __align__(16) unsigned short lB[BN * BK];
    __shared__ int sTok[BM];
    __shared__ int sSlot[BM];
    __shared__ float sGate[BM];

    int tid = threadIdx.x;
    if (tid < BM) {
        int m = m0 + tid;
        int mc = m < M ? m : M - 1;
        sTok[tid] = tokL[e * TT + mc];
        sSlot[tid] = slotL[e * TT + mc];
        sGate[tid] = gateL[e * TT + mc];
    }
    __syncthreads();

    int ar = tid >> 3, ac = tid & 7;
    const unsigned short* aP[4];
    #pragma unroll
    for (int i = 0; i < 4; ++i)
        aP[i] = Hb + (size_t)sSlot[ar + 32 * i] * ITR + ac * 8;

    int br = tid >> 4, bc = tid & 15;
    const float* dB = Wd + ((size_t)e * HID + n0) * ITR + bc * 4;

    int wv = tid >> 6, lane = tid & 63;
    int wm = (wv >> 1) * 64, wn = (wv & 1) * 64;
    int lr = lane & 15, lk = (lane >> 4) * 8;

    acc4 zero4 = {0.f, 0.f, 0.f, 0.f};
    acc4 a4[4][4];
    #pragma unroll
    for (int mi = 0; mi < 4; ++mi)
        #pragma unroll
        for (int ni = 0; ni < 4; ++ni) a4[mi][ni] = zero4;

    for (int k0 = 0; k0 < ITR; k0 += BK) {
        if (k0) __syncthreads();
        #pragma unroll
        for (int i = 0; i < 4; ++i) {
            int row = ar + 32 * i;
            s8v v = *(const s8v*)(aP[i] + k0);
            int byt = (row * 128 + ac * 16) ^ ((row & 7) << 4);
            *(s8v*)((char*)lA + byt) = v;
        }
        #pragma unroll
        for (int i = 0; i < 8; ++i) {
            int row = br + 16 * i;
            f4 vd = *(const f4*)(dB + (size_t)row * ITR + k0);
            u4v od = { f2bf(vd.x), f2bf(vd.y), f2bf(vd.z), f2bf(vd.w) };
            int byt = (row * 128 + bc * 8) ^ ((row & 7) << 4);
            *(u4v*)((char*)lB + byt) = od;
        }
        __syncthreads();
        #pragma unroll
        for (int kk = 0; kk < BK; kk += 32) {
            s8v af[4], bf[4];
            #pragma unroll
            for (int i = 0; i < 4; ++i) {
                int rowA = wm + i * 16 + lr;
                af[i] = *(const s8v*)((char*)lA + ((rowA * 128 + (kk + lk) * 2) ^ ((rowA & 7) << 4)));
                int rowB = wn + i * 16 + lr;
                bf[i] = *(const s8v*)((char*)lB + ((rowB * 128 + (kk + lk) * 2) ^ ((rowB & 7) << 4)));
            }
            #pragma unroll
            for (int mi = 0; mi < 4; ++mi)
                #pragma unroll
                for (int ni = 0; ni < 4; ++ni)
                    a4[mi][ni] = MFMA16(af[mi], bf[ni], a4[mi][ni]);
        }
    }
    #pragma unroll
    for (int mi = 0; mi < 4; ++mi) {
        #pragma unroll
        for (int j = 0; j < 4; ++j) {
            int m = wm + mi * 16 + (lane >> 4) * 4 + j;
            if (m0 + m < M) {
                int t = sTok[m];
                float w = sGate[m];
                float* orow = out + (size_t)t * HID + n0 + wn + lr;
                #pragma unroll
                for (int ni = 0; ni < 4; ++ni)
                    atomicAdd(orow + ni * 16, w * a4[mi][ni][j]);
            }
        }
    }
}

extern "C" void kernel_launch(void* const* d_in, const int* in_sizes, int n_in,
                              void* d_out, int out_size, void* d_ws, size_t ws_size,
                              hipStream_t stream) {
    const float* x  = (const float*)d_in[0];
    const float* rw = (const float*)d_in[1];
    const float* rb = (const float*)d_in[2];
    const float* Wg = (const float*)d_in[3];
    const float* Wu = (const float*)d_in[4];
    const float* Wd = (const float*)d_in[5];
    float* out = (float*)d_out;
    char* ws = (char*)d_ws;

    // ws layout (bytes):
    const size_t OFF_XB   = 0;                      // 32 MB
    const size_t OFF_HB   = 33554432ull;            // 176 MB
    const size_t OFF_TOK  = 218103808ull;
    const size_t OFF_SLOT = 218365952ull;
    const size_t OFF_GATE = 218628096ull;
    const size_t OFF_CNT  = 218890240ull;
    const size_t OFF_WG   = 218891264ull;           // 176 MB
    const size_t OFF_WU   = 403440640ull;           // 176 MB
    const size_t OFF_WD   = 587990016ull;           // 176 MB
    const size_t NEED     = 772539392ull;

    unsigned short* xb   = (unsigned short*)(ws + OFF_XB);
    unsigned short* Hb   = (unsigned short*)(ws + OFF_HB);
    int*   tokL  = (int*)(ws + OFF_TOK);
    int*   slotL = (int*)(ws + OFF_SLOT);
    float* gateL = (float*)(ws + OFF_GATE);
    int*   cnt   = (int*)(ws + OFF_CNT);

    hipMemsetAsync(cnt, 0, NE * sizeof(int), stream);
    hipMemsetAsync(out, 0, (size_t)out_size * sizeof(float), stream);
    k_xrt<<<2048, 256, 0, stream>>>(x, rw, rb, xb, cnt, tokL, slotL, gateL);

    if (ws_size >= NEED) {
        unsigned short* WgB = (unsigned short*)(ws + OFF_WG);
        unsigned short* WuB = (unsigned short*)(ws + OFF_WU);
        unsigned short* WdB = (unsigned short*)(ws + OFF_WD);
        k_cvtGU<<<2 * WBLK, 256, 0, stream>>>(Wg, Wu, WgB, WuB);
        k_gemm1b<<<NE * MT1 * NT1, 256, 0, stream>>>(xb, WgB, WuB, Wd, WdB, cnt, tokL, slotL, Hb);
        k_gemm2b<<<NE * MT1 * NT2, 256, 0, stream>>>(Hb, WdB, cnt, tokL, slotL, gateL, out);
    } else {
        k_gemm1<<<NE * MT1 * NT1, 256, 0, stream>>>(xb, Wg, Wu, cnt, tokL, slotL, Hb);
        k_gemm2<<<NE * MT1 * NT2, 256, 0, stream>>>(Hb, Wd, cnt, tokL, slotL, gateL, out);
    }
}

// Round 10
// 1855.893 us; speedup vs baseline: 1.4527x; 1.4527x over previous
//
#include <hip/hip_runtime.h>
#include <stdint.h>

#define HID 2048
#define ITR 5632
#define NE 8
#define TT 8192
#define BM 128
#define BN 128
#define BK 64
#define MT1 64          // max m-tiles per expert (8192/128)
#define NT1 44          // ITR/BN
#define NT2 16          // HID/BN
#define WBLK 45056      // fp32->bf16 2048-elem chunks per weight tensor

typedef __attribute__((ext_vector_type(4))) float f4;
typedef __attribute__((ext_vector_type(8))) short s8v;      // 8 bf16 (MFMA frag)
typedef __attribute__((ext_vector_type(4))) float acc4;     // MFMA accum
typedef __attribute__((ext_vector_type(4))) unsigned short u4v;
typedef __attribute__((ext_vector_type(8))) unsigned short u8v;

__device__ __forceinline__ unsigned short f2bf(float f) {
    union { float f; uint32_t u; } v; v.f = f;
    uint32_t u = v.u;
    return (unsigned short)((u + 0x7FFFu + ((u >> 16) & 1u)) >> 16);
}

__device__ __forceinline__ void gload16(const unsigned short* g, unsigned short* l) {
    __builtin_amdgcn_global_load_lds(
        (const __attribute__((address_space(1))) unsigned int*)g,
        (__attribute__((address_space(3))) unsigned int*)l, 16, 0, 0);
}

#define MFMA16(a, b, c) __builtin_amdgcn_mfma_f32_16x16x32_bf16(a, b, c, 0, 0, 0)

// ---------- fused: x fp32 -> bf16 AND router top-2 ----------
__global__ __launch_bounds__(256) void k_xrt(const float* __restrict__ x,
                                             const float* __restrict__ rw,
                                             const float* __restrict__ rb,
                                             unsigned short* __restrict__ xb,
                                             int* __restrict__ cnt,
                                             int* __restrict__ tokL,
                                             int* __restrict__ slotL,
                                             float* __restrict__ gateL) {
    int lane = threadIdx.x & 63;
    int wv = threadIdx.x >> 6;
    int t = blockIdx.x * 4 + wv;
    const float* xr = x + (size_t)t * HID;
    unsigned short* xo = xb + (size_t)t * HID;
    float acc[NE];
    #pragma unroll
    for (int e = 0; e < NE; ++e) acc[e] = 0.f;
    #pragma unroll
    for (int i = 0; i < 8; ++i) {
        f4 xv = *(const f4*)(xr + i * 256 + lane * 4);
        u4v o = { f2bf(xv.x), f2bf(xv.y), f2bf(xv.z), f2bf(xv.w) };
        *(u4v*)(xo + i * 256 + lane * 4) = o;
        #pragma unroll
        for (int e = 0; e < NE; ++e) {
            f4 wv4 = *(const f4*)(rw + e * HID + i * 256 + lane * 4);
            acc[e] += xv.x * wv4.x + xv.y * wv4.y + xv.z * wv4.z + xv.w * wv4.w;
        }
    }
    #pragma unroll
    for (int off = 32; off; off >>= 1)
        #pragma unroll
        for (int e = 0; e < NE; ++e) acc[e] += __shfl_xor(acc[e], off, 64);
    if (lane == 0) {
        float lg[NE];
        #pragma unroll
        for (int e = 0; e < NE; ++e) lg[e] = acc[e] + rb[e];
        int i1 = 0;
        #pragma unroll
        for (int e = 1; e < NE; ++e) if (lg[e] > lg[i1]) i1 = e;   // earliest max (jax tie rule)
        int i2 = -1;
        #pragma unroll
        for (int e = 0; e < NE; ++e) {
            if (e == i1) continue;
            if (i2 < 0 || lg[e] > lg[i2]) i2 = e;
        }
        float ex = __expf(lg[i2] - lg[i1]);   // <= 1
        float w1 = 1.f / (1.f + ex);
        float w2 = ex / (1.f + ex);
        int p = atomicAdd(&cnt[i1], 1);
        tokL[i1 * TT + p] = t; slotL[i1 * TT + p] = t * 2;     gateL[i1 * TT + p] = w1;
        p = atomicAdd(&cnt[i2], 1);
        tokL[i2 * TT + p] = t; slotL[i2 * TT + p] = t * 2 + 1; gateL[i2 * TT + p] = w2;
    }
}

// ---------- all three weight tensors fp32 -> bf16, grid-stride ----------
// 3072 blocks x 256 thr; each block converts ~44 independent 2048-elem chunks
// (loop iterations independent -> many loads in flight per wave).
#define CVT_BLOCKS 3072
__global__ __launch_bounds__(256) void k_cvtW3(const float* __restrict__ a,
                                               const float* __restrict__ b,
                                               const float* __restrict__ c,
                                               unsigned short* __restrict__ oa,
                                               unsigned short* __restrict__ ob,
                                               unsigned short* __restrict__ oc) {
    int tid = threadIdx.x;
    for (int ch = blockIdx.x; ch < 3 * WBLK; ch += CVT_BLOCKS) {
        int bb = ch;
        const float* s; unsigned short* d;
        if (bb < WBLK)            { s = a; d = oa; }
        else if (bb < 2 * WBLK)   { s = b; d = ob; bb -= WBLK; }
        else                      { s = c; d = oc; bb -= 2 * WBLK; }
        size_t i = ((size_t)bb * 256 + tid) * 8;
        f4 va = *(const f4*)(s + i);
        f4 vb = *(const f4*)(s + i + 4);
        u8v o;
        o[0]=f2bf(va.x); o[1]=f2bf(va.y); o[2]=f2bf(va.z); o[3]=f2bf(va.w);
        o[4]=f2bf(vb.x); o[5]=f2bf(vb.y); o[6]=f2bf(vb.z); o[7]=f2bf(vb.w);
        *(u8v*)(d + i) = o;
    }
}

// ============================================================================
// FAST PATH (round-8 measured best, byte-identical GEMMs): bf16 weights,
// global_load_lds staging, 128x128 tile, BK=64, XOR swizzle ^((row&7)<<4),
// linear grid (nt fastest), idle blocks exit immediately.
// ============================================================================

// ---------- GEMM1: Hb[slot] = silu(X Wg^T) * (X Wu^T), bf16 ----------
__global__ __launch_bounds__(256, 2) void k_gemm1b(const unsigned short* __restrict__ xb,
                                                   const unsigned short* __restrict__ WgB,
                                                   const unsigned short* __restrict__ WuB,
                                                   const int* __restrict__ cnt,
                                                   const int* __restrict__ tokL,
                                                   const int* __restrict__ slotL,
                                                   unsigned short* __restrict__ Hb) {
    int bx = blockIdx.x;
    int e = bx / (MT1 * NT1);
    int r = bx % (MT1 * NT1);
    int mt = r / NT1, nt = r % NT1;
    int M = cnt[e];
    int m0 = mt * BM;
    if (m0 >= M) return;
    int n0 = nt * BN;

    __shared__ __align__(16) unsigned short lA[BM * BK];
    __shared__ __align__(16) unsigned short lBg[BN * BK];
    __shared__ __align__(16) unsigned short lBu[BN * BK];
    __shared__ int sTok[BM];
    __shared__ int sSlot[BM];

    int tid = threadIdx.x;
    if (tid < BM) {
        int m = m0 + tid;
        int mc = m < M ? m : M - 1;
        sTok[tid] = tokL[e * TT + mc];
        sSlot[tid] = slotL[e * TT + mc];
    }
    __syncthreads();

    int wv = tid >> 6, lane = tid & 63;
    int subrow = lane >> 3;                      // 0..7 = row within 8-row chunk
    int colE = ((lane & 7) ^ subrow) * 8;        // inverse-swizzled source col (elems)

    const unsigned short* aSrc[4];
    const unsigned short* gSrc[4];
    const unsigned short* uSrc[4];
    #pragma unroll
    for (int i = 0; i < 4; ++i) {
        int row = (i * 4 + wv) * 8 + subrow;
        aSrc[i] = xb + (size_t)sTok[row] * HID + colE;
        gSrc[i] = WgB + ((size_t)e * ITR + n0 + row) * HID + colE;
        uSrc[i] = WuB + ((size_t)e * ITR + n0 + row) * HID + colE;
    }

    int wm = (wv >> 1) * 64, wn = (wv & 1) * 64;
    int lr = lane & 15, lk = (lane >> 4) * 8;

    acc4 zero4 = {0.f, 0.f, 0.f, 0.f};
    acc4 ag[4][4], au[4][4];
    #pragma unroll
    for (int mi = 0; mi < 4; ++mi)
        #pragma unroll
        for (int ni = 0; ni < 4; ++ni) { ag[mi][ni] = zero4; au[mi][ni] = zero4; }

    for (int k0 = 0; k0 < HID; k0 += BK) {
        if (k0) __syncthreads();
        #pragma unroll
        for (int i = 0; i < 4; ++i) {
            gload16(aSrc[i] + k0, lA  + (i * 4 + wv) * 512);
            gload16(gSrc[i] + k0, lBg + (i * 4 + wv) * 512);
            gload16(uSrc[i] + k0, lBu + (i * 4 + wv) * 512);
        }
        __syncthreads();
        #pragma unroll
        for (int kk = 0; kk < BK; kk += 32) {
            s8v af[4], gf[4], uf[4];
            #pragma unroll
            for (int i = 0; i < 4; ++i) {
                int rowA = wm + i * 16 + lr;
                af[i] = *(const s8v*)((char*)lA + ((rowA * 128 + (kk + lk) * 2) ^ ((rowA & 7) << 4)));
                int rowB = wn + i * 16 + lr;
                int bb = (rowB * 128 + (kk + lk) * 2) ^ ((rowB & 7) << 4);
                gf[i] = *(const s8v*)((char*)lBg + bb);
                uf[i] = *(const s8v*)((char*)lBu + bb);
            }
            #pragma unroll
            for (int mi = 0; mi < 4; ++mi)
                #pragma unroll
                for (int ni = 0; ni < 4; ++ni) {
                    ag[mi][ni] = MFMA16(af[mi], gf[ni], ag[mi][ni]);
                    au[mi][ni] = MFMA16(af[mi], uf[ni], au[mi][ni]);
                }
        }
    }
    #pragma unroll
    for (int mi = 0; mi < 4; ++mi) {
        #pragma unroll
        for (int j2 = 0; j2 < 4; ++j2) {
            int m = wm + mi * 16 + (lane >> 4) * 4 + j2;
            if (m0 + m < M) {
                size_t rowOff = (size_t)sSlot[m] * ITR + n0 + wn + lr;
                #pragma unroll
                for (int ni = 0; ni < 4; ++ni) {
                    float g = ag[mi][ni][j2], u = au[mi][ni][j2];
                    float h = g * (1.f / (1.f + __expf(-g))) * u;
                    Hb[rowOff + ni * 16] = f2bf(h);
                }
            }
        }
    }
}

// ---------- GEMM2: out[t] += gate * (Hb[slot] Wd^T) ----------
__global__ __launch_bounds__(256, 3) void k_gemm2b(const unsigned short* __restrict__ Hb,
                                                   const unsigned short* __restrict__ WdB,
                                                   const int* __restrict__ cnt,
                                                   const int* __restrict__ tokL,
                                                   const int* __restrict__ slotL,
                                                   const float* __restrict__ gateL,
                                                   float* __restrict__ out) {
    int bx = blockIdx.x;
    int e = bx / (MT1 * NT2);
    int r = bx % (MT1 * NT2);
    int mt = r / NT2, nt = r % NT2;
    int M = cnt[e];
    int m0 = mt * BM;
    if (m0 >= M) return;
    int n0 = nt * BN;

    __shared__ __align__(16) unsigned short lA[BM * BK];
    __shared__ __align__(16) unsigned short lB[BN * BK];
    __shared__ int sTok[BM];
    __shared__ int sSlot[BM];
    __shared__ float sGate[BM];

    int tid = threadIdx.x;
    if (tid < BM) {
        int m = m0 + tid;
        int mc = m < M ? m : M - 1;
        sTok[tid] = tokL[e * TT + mc];
        sSlot[tid] = slotL[e * TT + mc];
        sGate[tid] = gateL[e * TT + mc];
    }
    __syncthreads();

    int wv = tid >> 6, lane = tid & 63;
    int subrow = lane >> 3;
    int colE = ((lane & 7) ^ subrow) * 8;

    const unsigned short* aSrc[4];
    const unsigned short* bSrc[4];
    #pragma unroll
    for (int i = 0; i < 4; ++i) {
        int row = (i * 4 + wv) * 8 + subrow;
        aSrc[i] = Hb + (size_t)sSlot[row] * ITR + colE;
        bSrc[i] = WdB + ((size_t)e * HID + n0 + row) * ITR + colE;
    }

    int wm = (wv >> 1) * 64, wn = (wv & 1) * 64;
    int lr = lane & 15, lk = (lane >> 4) * 8;

    acc4 zero4 = {0.f, 0.f, 0.f, 0.f};
    acc4 a4[4][4];
    #pragma unroll
    for (int mi = 0; mi < 4; ++mi)
        #pragma unroll
        for (int ni = 0; ni < 4; ++ni) a4[mi][ni] = zero4;

    for (int k0 = 0; k0 < ITR; k0 += BK) {
        if (k0) __syncthreads();
        #pragma unroll
        for (int i = 0; i < 4; ++i) {
            gload16(aSrc[i] + k0, lA + (i * 4 + wv) * 512);
            gload16(bSrc[i] + k0, lB + (i * 4 + wv) * 512);
        }
        __syncthreads();
        #pragma unroll
        for (int kk = 0; kk < BK; kk += 32) {
            s8v af[4], bf[4];
            #pragma unroll
            for (int i = 0; i < 4; ++i) {
                int rowA = wm + i * 16 + lr;
                af[i] = *(const s8v*)((char*)lA + ((rowA * 128 + (kk + lk) * 2) ^ ((rowA & 7) << 4)));
                int rowB = wn + i * 16 + lr;
                bf[i] = *(const s8v*)((char*)lB + ((rowB * 128 + (kk + lk) * 2) ^ ((rowB & 7) << 4)));
            }
            #pragma unroll
            for (int mi = 0; mi < 4; ++mi)
                #pragma unroll
                for (int ni = 0; ni < 4; ++ni)
                    a4[mi][ni] = MFMA16(af[mi], bf[ni], a4[mi][ni]);
        }
    }
    #pragma unroll
    for (int mi = 0; mi < 4; ++mi) {
        #pragma unroll
        for (int j2 = 0; j2 < 4; ++j2) {
            int m = wm + mi * 16 + (lane >> 4) * 4 + j2;
            if (m0 + m < M) {
                int t = sTok[m];
                float w = sGate[m];
                float* orow = out + (size_t)t * HID + n0 + wn + lr;
                #pragma unroll
                for (int ni = 0; ni < 4; ++ni)
                    atomicAdd(orow + ni * 16, w * a4[mi][ni][j2]);
            }
        }
    }
}

// ============================================================================
// FALLBACK PATH (fp32 weights staged in-kernel) — only if ws too small.
// ============================================================================

__global__ __launch_bounds__(256) void k_gemm1(const unsigned short* __restrict__ xb,
                                               const float* __restrict__ Wg,
                                               const float* __restrict__ Wu,
                                               const int* __restrict__ cnt,
                                               const int* __restrict__ tokL,
                                               const int* __restrict__ slotL,
                                               unsigned short* __restrict__ Hb) {
    int bx = blockIdx.x;
    int e = bx / (MT1 * NT1);
    int r = bx % (MT1 * NT1);
    int mt = r / NT1, nt = r % NT1;
    int M = cnt[e];
    int m0 = mt * BM;
    if (m0 >= M) return;
    int n0 = nt * BN;

    __shared__ __align__(16) unsigned short lA[BM * BK];
    __shared__ __align__(16) unsigned short lBg[BN * BK];
    __shared__ __align__(16) unsigned short lBu[BN * BK];
    __shared__ int sTok[BM];
    __shared__ int sSlot[BM];

    int tid = threadIdx.x;
    if (tid < BM) {
        int m = m0 + tid;
        int mc = m < M ? m : M - 1;
        sTok[tid] = tokL[e * TT + mc];
        sSlot[tid] = slotL[e * TT + mc];
    }
    __syncthreads();

    int ar = tid >> 3, ac = tid & 7;
    const unsigned short* aP[4];
    #pragma unroll
    for (int i = 0; i < 4; ++i)
        aP[i] = xb + (size_t)sTok[ar + 32 * i] * HID + ac * 8;

    int br = tid >> 4, bc = tid & 15;
    const float* gB = Wg + ((size_t)e * ITR + n0) * HID + bc * 4;
    const float* uB = Wu + ((size_t)e * ITR + n0) * HID + bc * 4;

    int wv = tid >> 6, lane = tid & 63;
    int wm = (wv >> 1) * 64, wn = (wv & 1) * 64;
    int lr = lane & 15, lk = (lane >> 4) * 8;

    acc4 zero4 = {0.f, 0.f, 0.f, 0.f};
    acc4 ag[4][4], au[4][4];
    #pragma unroll
    for (int mi = 0; mi < 4; ++mi)
        #pragma unroll
        for (int ni = 0; ni < 4; ++ni) { ag[mi][ni] = zero4; au[mi][ni] = zero4; }

    for (int k0 = 0; k0 < HID; k0 += BK) {
        if (k0) __syncthreads();
        #pragma unroll
        for (int i = 0; i < 4; ++i) {
            int row = ar + 32 * i;
            s8v v = *(const s8v*)(aP[i] + k0);
            int byt = (row * 128 + ac * 16) ^ ((row & 7) << 4);
            *(s8v*)((char*)lA + byt) = v;
        }
        #pragma unroll
        for (int i = 0; i < 8; ++i) {
            int row = br + 16 * i;
            f4 vg = *(const f4*)(gB + (size_t)row * HID + k0);
            f4 vu = *(const f4*)(uB + (size_t)row * HID + k0);
            u4v og = { f2bf(vg.x), f2bf(vg.y), f2bf(vg.z), f2bf(vg.w) };
            u4v ou = { f2bf(vu.x), f2bf(vu.y), f2bf(vu.z), f2bf(vu.w) };
            int byt = (row * 128 + bc * 8) ^ ((row & 7) << 4);
            *(u4v*)((char*)lBg + byt) = og;
            *(u4v*)((char*)lBu + byt) = ou;
        }
        __syncthreads();
        #pragma unroll
        for (int kk = 0; kk < BK; kk += 32) {
            s8v af[4], gf[4], uf[4];
            #pragma unroll
            for (int i = 0; i < 4; ++i) {
                int rowA = wm + i * 16 + lr;
                af[i] = *(const s8v*)((char*)lA + ((rowA * 128 + (kk + lk) * 2) ^ ((rowA & 7) << 4)));
                int rowB = wn + i * 16 + lr;
                int bb = (rowB * 128 + (kk + lk) * 2) ^ ((rowB & 7) << 4);
                gf[i] = *(const s8v*)((char*)lBg + bb);
                uf[i] = *(const s8v*)((char*)lBu + bb);
            }
            #pragma unroll
            for (int mi = 0; mi < 4; ++mi)
                #pragma unroll
                for (int ni = 0; ni < 4; ++ni) {
                    ag[mi][ni] = MFMA16(af[mi], gf[ni], ag[mi][ni]);
                    au[mi][ni] = MFMA16(af[mi], uf[ni], au[mi][ni]);
                }
        }
    }
    #pragma unroll
    for (int mi = 0; mi < 4; ++mi) {
        #pragma unroll
        for (int j = 0; j < 4; ++j) {
            int m = wm + mi * 16 + (lane >> 4) * 4 + j;
            if (m0 + m < M) {
                size_t rowOff = (size_t)sSlot[m] * ITR + n0 + wn + lr;
                #pragma unroll
                for (int ni = 0; ni < 4; ++ni) {
                    float g = ag[mi][ni][j], u = au[mi][ni][j];
                    float h = g * (1.f / (1.f + __expf(-g))) * u;
                    Hb[rowOff + ni * 16] = f2bf(h);
                }
            }
        }
    }
}

__global__ __launch_bounds__(256) void k_gemm2(const unsigned short* __restrict__ Hb,
                                               const float* __restrict__ Wd,
                                               const int* __restrict__ cnt,
                                               const int* __restrict__ tokL,
                                               const int* __restrict__ slotL,
                                               const float* __restrict__ gateL,
                                               float* __restrict__ out) {
    int bx = blockIdx.x;
    int e = bx / (MT1 * NT2);
    int r = bx % (MT1 * NT2);
    int mt = r / NT2, nt = r % NT2;
    int M = cnt[e];
    int m0 = mt * BM;
    if (m0 >= M) return;
    int n0 = nt * BN;

    __shared__ __align__(16) unsigned short lA[BM * BK];
    __shared__ __align__(16) unsigned short lB[BN * BK];
    __shared__ int sTok[BM];
    __shared__ int sSlot[BM];
    __shared__ float sGate[BM];

    int tid = threadIdx.x;
    if (tid < BM) {
        int m = m0 + tid;
        int mc = m < M ? m : M - 1;
        sTok[tid] = tokL[e * TT + mc];
        sSlot[tid] = slotL[e * TT + mc];
        sGate[tid] = gateL[e * TT + mc];
    }
    __syncthreads();

    int ar = tid >> 3, ac = tid & 7;
    const unsigned short* aP[4];
    #pragma unroll
    for (int i = 0; i < 4; ++i)
        aP[i] = Hb + (size_t)sSlot[ar + 32 * i] * ITR + ac * 8;

    int br = tid >> 4, bc = tid & 15;
    const float* dB = Wd + ((size_t)e * HID + n0) * ITR + bc * 4;

    int wv = tid >> 6, lane = tid & 63;
    int wm = (wv >> 1) * 64, wn = (wv & 1) * 64;
    int lr = lane & 15, lk = (lane >> 4) * 8;

    acc4 zero4 = {0.f, 0.f, 0.f, 0.f};
    acc4 a4[4][4];
    #pragma unroll
    for (int mi = 0; mi < 4; ++mi)
        #pragma unroll
        for (int ni = 0; ni < 4; ++ni) a4[mi][ni] = zero4;

    for (int k0 = 0; k0 < ITR; k0 += BK) {
        if (k0) __syncthreads();
        #pragma unroll
        for (int i = 0; i < 4; ++i) {
            int row = ar + 32 * i;
            s8v v = *(const s8v*)(aP[i] + k0);
            int byt = (row * 128 + ac * 16) ^ ((row & 7) << 4);
            *(s8v*)((char*)lA + byt) = v;
        }
        #pragma unroll
        for (int i = 0; i < 8; ++i) {
            int row = br + 16 * i;
            f4 vd = *(const f4*)(dB + (size_t)row * ITR + k0);
            u4v od = { f2bf(vd.x), f2bf(vd.y), f2bf(vd.z), f2bf(vd.w) };
            int byt = (row * 128 + bc * 8) ^ ((row & 7) << 4);
            *(u4v*)((char*)lB + byt) = od;
        }
        __syncthreads();
        #pragma unroll
        for (int kk = 0; kk < BK; kk += 32) {
            s8v af[4], bf[4];
            #pragma unroll
            for (int i = 0; i < 4; ++i) {
                int rowA = wm + i * 16 + lr;
                af[i] = *(const s8v*)((char*)lA + ((rowA * 128 + (kk + lk) * 2) ^ ((rowA & 7) << 4)));
                int rowB = wn + i * 16 + lr;
                bf[i] = *(const s8v*)((char*)lB + ((rowB * 128 + (kk + lk) * 2) ^ ((rowB & 7) << 4)));
            }
            #pragma unroll
            for (int mi = 0; mi < 4; ++mi)
                #pragma unroll
                for (int ni = 0; ni < 4; ++ni)
                    a4[mi][ni] = MFMA16(af[mi], bf[ni], a4[mi][ni]);
        }
    }
    #pragma unroll
    for (int mi = 0; mi < 4; ++mi) {
        #pragma unroll
        for (int j = 0; j < 4; ++j) {
            int m = wm + mi * 16 + (lane >> 4) * 4 + j;
            if (m0 + m < M) {
                int t = sTok[m];
                float w = sGate[m];
                float* orow = out + (size_t)t * HID + n0 + wn + lr;
                #pragma unroll
                for (int ni = 0; ni < 4; ++ni)
                    atomicAdd(orow + ni * 16, w * a4[mi][ni][j]);
            }
        }
    }
}

extern "C" void kernel_launch(void* const* d_in, const int* in_sizes, int n_in,
                              void* d_out, int out_size, void* d_ws, size_t ws_size,
                              hipStream_t stream) {
    const float* x  = (const float*)d_in[0];
    const float* rw = (const float*)d_in[1];
    const float* rb = (const float*)d_in[2];
    const float* Wg = (const float*)d_in[3];
    const float* Wu = (const float*)d_in[4];
    const float* Wd = (const float*)d_in[5];
    float* out = (float*)d_out;
    char* ws = (char*)d_ws;

    // ws layout (bytes):
    const size_t OFF_XB   = 0;                      // 32 MB
    const size_t OFF_HB   = 33554432ull;            // 176 MB
    const size_t OFF_TOK  = 218103808ull;
    const size_t OFF_SLOT = 218365952ull;
    const size_t OFF_GATE = 218628096ull;
    const size_t OFF_CNT  = 218890240ull;
    const size_t OFF_WG   = 218891264ull;           // 176 MB
    const size_t OFF_WU   = 403440640ull;           // 176 MB
    const size_t OFF_WD   = 587990016ull;           // 176 MB
    const size_t NEED     = 772539392ull;

    unsigned short* xb   = (unsigned short*)(ws + OFF_XB);
    unsigned short* Hb   = (unsigned short*)(ws + OFF_HB);
    int*   tokL  = (int*)(ws + OFF_TOK);
    int*   slotL = (int*)(ws + OFF_SLOT);
    float* gateL = (float*)(ws + OFF_GATE);
    int*   cnt   = (int*)(ws + OFF_CNT);

    hipMemsetAsync(cnt, 0, NE * sizeof(int), stream);
    hipMemsetAsync(out, 0, (size_t)out_size * sizeof(float), stream);
    k_xrt<<<2048, 256, 0, stream>>>(x, rw, rb, xb, cnt, tokL, slotL, gateL);

    if (ws_size >= NEED) {
        unsigned short* WgB = (unsigned short*)(ws + OFF_WG);
        unsigned short* WuB = (unsigned short*)(ws + OFF_WU);
        unsigned short* WdB = (unsigned short*)(ws + OFF_WD);
        k_cvtW3<<<CVT_BLOCKS, 256, 0, stream>>>(Wg, Wu, Wd, WgB, WuB, WdB);
        k_gemm1b<<<NE * MT1 * NT1, 256, 0, stream>>>(xb, WgB, WuB, cnt, tokL, slotL, Hb);
        k_gemm2b<<<NE * MT1 * NT2, 256, 0, stream>>>(Hb, WdB, cnt, tokL, slotL, gateL, out);
    } else {
        k_gemm1<<<NE * MT1 * NT1, 256, 0, stream>>>(xb, Wg, Wu, cnt, tokL, slotL, Hb);
        k_gemm2<<<NE * MT1 * NT2, 256, 0, stream>>>(Hb, Wd, cnt, tokL, slotL, gateL, out);
    }
}

// Round 11
// 1823.380 us; speedup vs baseline: 1.4786x; 1.0178x over previous
//
#include <hip/hip_runtime.h>
#include <stdint.h>

#define HID 2048
#define ITR 5632
#define NE 8
#define TT 8192
#define BM 128
#define BN 128
#define BK 64
#define MT1 64          // max m-tiles per expert (8192/128)
#define NT1 44          // ITR/BN
#define NT2 16          // HID/BN
#define WBLK 45056      // fp32->bf16 2048-elem chunks per weight tensor
#define XRT_BLOCKS 2048 // token blocks (4 tokens each) in the fused front kernel

typedef __attribute__((ext_vector_type(4))) float f4;
typedef __attribute__((ext_vector_type(8))) short s8v;      // 8 bf16 (MFMA frag)
typedef __attribute__((ext_vector_type(4))) float acc4;     // MFMA accum
typedef __attribute__((ext_vector_type(4))) unsigned short u4v;
typedef __attribute__((ext_vector_type(8))) unsigned short u8v;

__device__ __forceinline__ unsigned short f2bf(float f) {
    union { float f; uint32_t u; } v; v.f = f;
    uint32_t u = v.u;
    return (unsigned short)((u + 0x7FFFu + ((u >> 16) & 1u)) >> 16);
}

__device__ __forceinline__ void gload16(const unsigned short* g, unsigned short* l) {
    __builtin_amdgcn_global_load_lds(
        (const __attribute__((address_space(1))) unsigned int*)g,
        (__attribute__((address_space(3))) unsigned int*)l, 16, 0, 0);
}

#define MFMA16(a, b, c) __builtin_amdgcn_mfma_f32_16x16x32_bf16(a, b, c, 0, 0, 0)

// ---------- fused front kernel: x->bf16 + router (blocks 0..2047),
//            weight fp32->bf16 micro-chunks (blocks 2048..2048+3*WBLK-1) ----------
// The two halves are independent; fusing them into one launch overlaps the
// router's VALU/shuffle/atomic work with the conversion's BW streaming and
// saves a launch gap. Conversion uses the r8-measured-best micro-block form
// (one 2048-elem chunk per block: dispatch-parallel, TLP-saturated).
__global__ __launch_bounds__(256) void k_front(const float* __restrict__ x,
                                               const float* __restrict__ rw,
                                               const float* __restrict__ rb,
                                               unsigned short* __restrict__ xb,
                                               int* __restrict__ cnt,
                                               int* __restrict__ tokL,
                                               int* __restrict__ slotL,
                                               float* __restrict__ gateL,
                                               const float* __restrict__ Wg,
                                               const float* __restrict__ Wu,
                                               const float* __restrict__ Wd,
                                               unsigned short* __restrict__ WgB,
                                               unsigned short* __restrict__ WuB,
                                               unsigned short* __restrict__ WdB) {
    int tid = threadIdx.x;
    if (blockIdx.x >= XRT_BLOCKS) {
        // -------- weight conversion duty: one 8KB chunk per block --------
        int bb = blockIdx.x - XRT_BLOCKS;
        const float* s; unsigned short* d;
        if (bb < WBLK)            { s = Wg; d = WgB; }
        else if (bb < 2 * WBLK)   { s = Wu; d = WuB; bb -= WBLK; }
        else                      { s = Wd; d = WdB; bb -= 2 * WBLK; }
        size_t i = ((size_t)bb * 256 + tid) * 8;
        f4 va = *(const f4*)(s + i);
        f4 vb = *(const f4*)(s + i + 4);
        u8v o;
        o[0]=f2bf(va.x); o[1]=f2bf(va.y); o[2]=f2bf(va.z); o[3]=f2bf(va.w);
        o[4]=f2bf(vb.x); o[5]=f2bf(vb.y); o[6]=f2bf(vb.z); o[7]=f2bf(vb.w);
        *(u8v*)(d + i) = o;
        return;
    }
    // -------- x -> bf16 + router top-2 (1 token/wave, 4 waves/block) --------
    int lane = tid & 63;
    int wv = tid >> 6;
    int t = blockIdx.x * 4 + wv;
    const float* xr = x + (size_t)t * HID;
    unsigned short* xo = xb + (size_t)t * HID;
    float acc[NE];
    #pragma unroll
    for (int e = 0; e < NE; ++e) acc[e] = 0.f;
    #pragma unroll
    for (int i = 0; i < 8; ++i) {
        f4 xv = *(const f4*)(xr + i * 256 + lane * 4);
        u4v o = { f2bf(xv.x), f2bf(xv.y), f2bf(xv.z), f2bf(xv.w) };
        *(u4v*)(xo + i * 256 + lane * 4) = o;
        #pragma unroll
        for (int e = 0; e < NE; ++e) {
            f4 wv4 = *(const f4*)(rw + e * HID + i * 256 + lane * 4);
            acc[e] += xv.x * wv4.x + xv.y * wv4.y + xv.z * wv4.z + xv.w * wv4.w;
        }
    }
    #pragma unroll
    for (int off = 32; off; off >>= 1)
        #pragma unroll
        for (int e = 0; e < NE; ++e) acc[e] += __shfl_xor(acc[e], off, 64);
    if (lane == 0) {
        float lg[NE];
        #pragma unroll
        for (int e = 0; e < NE; ++e) lg[e] = acc[e] + rb[e];
        int i1 = 0;
        #pragma unroll
        for (int e = 1; e < NE; ++e) if (lg[e] > lg[i1]) i1 = e;   // earliest max (jax tie rule)
        int i2 = -1;
        #pragma unroll
        for (int e = 0; e < NE; ++e) {
            if (e == i1) continue;
            if (i2 < 0 || lg[e] > lg[i2]) i2 = e;
        }
        float ex = __expf(lg[i2] - lg[i1]);   // <= 1
        float w1 = 1.f / (1.f + ex);
        float w2 = ex / (1.f + ex);
        int p = atomicAdd(&cnt[i1], 1);
        tokL[i1 * TT + p] = t; slotL[i1 * TT + p] = t * 2;     gateL[i1 * TT + p] = w1;
        p = atomicAdd(&cnt[i2], 1);
        tokL[i2 * TT + p] = t; slotL[i2 * TT + p] = t * 2 + 1; gateL[i2 * TT + p] = w2;
    }
}

// ============================================================================
// FAST PATH (round-8 measured best, byte-identical GEMMs): bf16 weights,
// global_load_lds staging, 128x128 tile, BK=64, XOR swizzle ^((row&7)<<4),
// linear grid (nt fastest), idle blocks exit immediately.
// ============================================================================

// ---------- GEMM1: Hb[slot] = silu(X Wg^T) * (X Wu^T), bf16 ----------
__global__ __launch_bounds__(256, 2) void k_gemm1b(const unsigned short* __restrict__ xb,
                                                   const unsigned short* __restrict__ WgB,
                                                   const unsigned short* __restrict__ WuB,
                                                   const int* __restrict__ cnt,
                                                   const int* __restrict__ tokL,
                                                   const int* __restrict__ slotL,
                                                   unsigned short* __restrict__ Hb) {
    int bx = blockIdx.x;
    int e = bx / (MT1 * NT1);
    int r = bx % (MT1 * NT1);
    int mt = r / NT1, nt = r % NT1;
    int M = cnt[e];
    int m0 = mt * BM;
    if (m0 >= M) return;
    int n0 = nt * BN;

    __shared__ __align__(16) unsigned short lA[BM * BK];
    __shared__ __align__(16) unsigned short lBg[BN * BK];
    __shared__ __align__(16) unsigned short lBu[BN * BK];
    __shared__ int sTok[BM];
    __shared__ int sSlot[BM];

    int tid = threadIdx.x;
    if (tid < BM) {
        int m = m0 + tid;
        int mc = m < M ? m : M - 1;
        sTok[tid] = tokL[e * TT + mc];
        sSlot[tid] = slotL[e * TT + mc];
    }
    __syncthreads();

    int wv = tid >> 6, lane = tid & 63;
    int subrow = lane >> 3;                      // 0..7 = row within 8-row chunk
    int colE = ((lane & 7) ^ subrow) * 8;        // inverse-swizzled source col (elems)

    const unsigned short* aSrc[4];
    const unsigned short* gSrc[4];
    const unsigned short* uSrc[4];
    #pragma unroll
    for (int i = 0; i < 4; ++i) {
        int row = (i * 4 + wv) * 8 + subrow;
        aSrc[i] = xb + (size_t)sTok[row] * HID + colE;
        gSrc[i] = WgB + ((size_t)e * ITR + n0 + row) * HID + colE;
        uSrc[i] = WuB + ((size_t)e * ITR + n0 + row) * HID + colE;
    }

    int wm = (wv >> 1) * 64, wn = (wv & 1) * 64;
    int lr = lane & 15, lk = (lane >> 4) * 8;

    acc4 zero4 = {0.f, 0.f, 0.f, 0.f};
    acc4 ag[4][4], au[4][4];
    #pragma unroll
    for (int mi = 0; mi < 4; ++mi)
        #pragma unroll
        for (int ni = 0; ni < 4; ++ni) { ag[mi][ni] = zero4; au[mi][ni] = zero4; }

    for (int k0 = 0; k0 < HID; k0 += BK) {
        if (k0) __syncthreads();
        #pragma unroll
        for (int i = 0; i < 4; ++i) {
            gload16(aSrc[i] + k0, lA  + (i * 4 + wv) * 512);
            gload16(gSrc[i] + k0, lBg + (i * 4 + wv) * 512);
            gload16(uSrc[i] + k0, lBu + (i * 4 + wv) * 512);
        }
        __syncthreads();
        #pragma unroll
        for (int kk = 0; kk < BK; kk += 32) {
            s8v af[4], gf[4], uf[4];
            #pragma unroll
            for (int i = 0; i < 4; ++i) {
                int rowA = wm + i * 16 + lr;
                af[i] = *(const s8v*)((char*)lA + ((rowA * 128 + (kk + lk) * 2) ^ ((rowA & 7) << 4)));
                int rowB = wn + i * 16 + lr;
                int bb = (rowB * 128 + (kk + lk) * 2) ^ ((rowB & 7) << 4);
                gf[i] = *(const s8v*)((char*)lBg + bb);
                uf[i] = *(const s8v*)((char*)lBu + bb);
            }
            #pragma unroll
            for (int mi = 0; mi < 4; ++mi)
                #pragma unroll
                for (int ni = 0; ni < 4; ++ni) {
                    ag[mi][ni] = MFMA16(af[mi], gf[ni], ag[mi][ni]);
                    au[mi][ni] = MFMA16(af[mi], uf[ni], au[mi][ni]);
                }
        }
    }
    #pragma unroll
    for (int mi = 0; mi < 4; ++mi) {
        #pragma unroll
        for (int j2 = 0; j2 < 4; ++j2) {
            int m = wm + mi * 16 + (lane >> 4) * 4 + j2;
            if (m0 + m < M) {
                size_t rowOff = (size_t)sSlot[m] * ITR + n0 + wn + lr;
                #pragma unroll
                for (int ni = 0; ni < 4; ++ni) {
                    float g = ag[mi][ni][j2], u = au[mi][ni][j2];
                    float h = g * (1.f / (1.f + __expf(-g))) * u;
                    Hb[rowOff + ni * 16] = f2bf(h);
                }
            }
        }
    }
}

// ---------- GEMM2: out[t] += gate * (Hb[slot] Wd^T) ----------
__global__ __launch_bounds__(256, 3) void k_gemm2b(const unsigned short* __restrict__ Hb,
                                                   const unsigned short* __restrict__ WdB,
                                                   const int* __restrict__ cnt,
                                                   const int* __restrict__ tokL,
                                                   const int* __restrict__ slotL,
                                                   const float* __restrict__ gateL,
                                                   float* __restrict__ out) {
    int bx = blockIdx.x;
    int e = bx / (MT1 * NT2);
    int r = bx % (MT1 * NT2);
    int mt = r / NT2, nt = r % NT2;
    int M = cnt[e];
    int m0 = mt * BM;
    if (m0 >= M) return;
    int n0 = nt * BN;

    __shared__ __align__(16) unsigned short lA[BM * BK];
    __shared__ __align__(16) unsigned short lB[BN * BK];
    __shared__ int sTok[BM];
    __shared__ int sSlot[BM];
    __shared__ float sGate[BM];

    int tid = threadIdx.x;
    if (tid < BM) {
        int m = m0 + tid;
        int mc = m < M ? m : M - 1;
        sTok[tid] = tokL[e * TT + mc];
        sSlot[tid] = slotL[e * TT + mc];
        sGate[tid] = gateL[e * TT + mc];
    }
    __syncthreads();

    int wv = tid >> 6, lane = tid & 63;
    int subrow = lane >> 3;
    int colE = ((lane & 7) ^ subrow) * 8;

    const unsigned short* aSrc[4];
    const unsigned short* bSrc[4];
    #pragma unroll
    for (int i = 0; i < 4; ++i) {
        int row = (i * 4 + wv) * 8 + subrow;
        aSrc[i] = Hb + (size_t)sSlot[row] * ITR + colE;
        bSrc[i] = WdB + ((size_t)e * HID + n0 + row) * ITR + colE;
    }

    int wm = (wv >> 1) * 64, wn = (wv & 1) * 64;
    int lr = lane & 15, lk = (lane >> 4) * 8;

    acc4 zero4 = {0.f, 0.f, 0.f, 0.f};
    acc4 a4[4][4];
    #pragma unroll
    for (int mi = 0; mi < 4; ++mi)
        #pragma unroll
        for (int ni = 0; ni < 4; ++ni) a4[mi][ni] = zero4;

    for (int k0 = 0; k0 < ITR; k0 += BK) {
        if (k0) __syncthreads();
        #pragma unroll
        for (int i = 0; i < 4; ++i) {
            gload16(aSrc[i] + k0, lA + (i * 4 + wv) * 512);
            gload16(bSrc[i] + k0, lB + (i * 4 + wv) * 512);
        }
        __syncthreads();
        #pragma unroll
        for (int kk = 0; kk < BK; kk += 32) {
            s8v af[4], bf[4];
            #pragma unroll
            for (int i = 0; i < 4; ++i) {
                int rowA = wm + i * 16 + lr;
                af[i] = *(const s8v*)((char*)lA + ((rowA * 128 + (kk + lk) * 2) ^ ((rowA & 7) << 4)));
                int rowB = wn + i * 16 + lr;
                bf[i] = *(const s8v*)((char*)lB + ((rowB * 128 + (kk + lk) * 2) ^ ((rowB & 7) << 4)));
            }
            #pragma unroll
            for (int mi = 0; mi < 4; ++mi)
                #pragma unroll
                for (int ni = 0; ni < 4; ++ni)
                    a4[mi][ni] = MFMA16(af[mi], bf[ni], a4[mi][ni]);
        }
    }
    #pragma unroll
    for (int mi = 0; mi < 4; ++mi) {
        #pragma unroll
        for (int j2 = 0; j2 < 4; ++j2) {
            int m = wm + mi * 16 + (lane >> 4) * 4 + j2;
            if (m0 + m < M) {
                int t = sTok[m];
                float w = sGate[m];
                float* orow = out + (size_t)t * HID + n0 + wn + lr;
                #pragma unroll
                for (int ni = 0; ni < 4; ++ni)
                    atomicAdd(orow + ni * 16, w * a4[mi][ni][j2]);
            }
        }
    }
}

// ============================================================================
// FALLBACK PATH (fp32 weights staged in-kernel) — only if ws too small.
// ============================================================================

__global__ __launch_bounds__(256) void k_xrt(const float* __restrict__ x,
                                             const float* __restrict__ rw,
                                             const float* __restrict__ rb,
                                             unsigned short* __restrict__ xb,
                                             int* __restrict__ cnt,
                                             int* __restrict__ tokL,
                                             int* __restrict__ slotL,
                                             float* __restrict__ gateL) {
    int lane = threadIdx.x & 63;
    int wv = threadIdx.x >> 6;
    int t = blockIdx.x * 4 + wv;
    const float* xr = x + (size_t)t * HID;
    unsigned short* xo = xb + (size_t)t * HID;
    float acc[NE];
    #pragma unroll
    for (int e = 0; e < NE; ++e) acc[e] = 0.f;
    #pragma unroll
    for (int i = 0; i < 8; ++i) {
        f4 xv = *(const f4*)(xr + i * 256 + lane * 4);
        u4v o = { f2bf(xv.x), f2bf(xv.y), f2bf(xv.z), f2bf(xv.w) };
        *(u4v*)(xo + i * 256 + lane * 4) = o;
        #pragma unroll
        for (int e = 0; e < NE; ++e) {
            f4 wv4 = *(const f4*)(rw + e * HID + i * 256 + lane * 4);
            acc[e] += xv.x * wv4.x + xv.y * wv4.y + xv.z * wv4.z + xv.w * wv4.w;
        }
    }
    #pragma unroll
    for (int off = 32; off; off >>= 1)
        #pragma unroll
        for (int e = 0; e < NE; ++e) acc[e] += __shfl_xor(acc[e], off, 64);
    if (lane == 0) {
        float lg[NE];
        #pragma unroll
        for (int e = 0; e < NE; ++e) lg[e] = acc[e] + rb[e];
        int i1 = 0;
        #pragma unroll
        for (int e = 1; e < NE; ++e) if (lg[e] > lg[i1]) i1 = e;
        int i2 = -1;
        #pragma unroll
        for (int e = 0; e < NE; ++e) {
            if (e == i1) continue;
            if (i2 < 0 || lg[e] > lg[i2]) i2 = e;
        }
        float ex = __expf(lg[i2] - lg[i1]);
        float w1 = 1.f / (1.f + ex);
        float w2 = ex / (1.f + ex);
        int p = atomicAdd(&cnt[i1], 1);
        tokL[i1 * TT + p] = t; slotL[i1 * TT + p] = t * 2;     gateL[i1 * TT + p] = w1;
        p = atomicAdd(&cnt[i2], 1);
        tokL[i2 * TT + p] = t; slotL[i2 * TT + p] = t * 2 + 1; gateL[i2 * TT + p] = w2;
    }
}

__global__ __launch_bounds__(256) void k_gemm1(const unsigned short* __restrict__ xb,
                                               const float* __restrict__ Wg,
                                               const float* __restrict__ Wu,
                                               const int* __restrict__ cnt,
                                               const int* __restrict__ tokL,
                                               const int* __restrict__ slotL,
                                               unsigned short* __restrict__ Hb) {
    int bx = blockIdx.x;
    int e = bx / (MT1 * NT1);
    int r = bx % (MT1 * NT1);
    int mt = r / NT1, nt = r % NT1;
    int M = cnt[e];
    int m0 = mt * BM;
    if (m0 >= M) return;
    int n0 = nt * BN;

    __shared__ __align__(16) unsigned short lA[BM * BK];
    __shared__ __align__(16) unsigned short lBg[BN * BK];
    __shared__ __align__(16) unsigned short lBu[BN * BK];
    __shared__ int sTok[BM];
    __shared__ int sSlot[BM];

    int tid = threadIdx.x;
    if (tid < BM) {
        int m = m0 + tid;
        int mc = m < M ? m : M - 1;
        sTok[tid] = tokL[e * TT + mc];
        sSlot[tid] = slotL[e * TT + mc];
    }
    __syncthreads();

    int ar = tid >> 3, ac = tid & 7;
    const unsigned short* aP[4];
    #pragma unroll
    for (int i = 0; i < 4; ++i)
        aP[i] = xb + (size_t)sTok[ar + 32 * i] * HID + ac * 8;

    int br = tid >> 4, bc = tid & 15;
    const float* gB = Wg + ((size_t)e * ITR + n0) * HID + bc * 4;
    const float* uB = Wu + ((size_t)e * ITR + n0) * HID + bc * 4;

    int wv = tid >> 6, lane = tid & 63;
    int wm = (wv >> 1) * 64, wn = (wv & 1) * 64;
    int lr = lane & 15, lk = (lane >> 4) * 8;

    acc4 zero4 = {0.f, 0.f, 0.f, 0.f};
    acc4 ag[4][4], au[4][4];
    #pragma unroll
    for (int mi = 0; mi < 4; ++mi)
        #pragma unroll
        for (int ni = 0; ni < 4; ++ni) { ag[mi][ni] = zero4; au[mi][ni] = zero4; }

    for (int k0 = 0; k0 < HID; k0 += BK) {
        if (k0) __syncthreads();
        #pragma unroll
        for (int i = 0; i < 4; ++i) {
            int row = ar + 32 * i;
            s8v v = *(const s8v*)(aP[i] + k0);
            int byt = (row * 128 + ac * 16) ^ ((row & 7) << 4);
            *(s8v*)((char*)lA + byt) = v;
        }
        #pragma unroll
        for (int i = 0; i < 8; ++i) {
            int row = br + 16 * i;
            f4 vg = *(const f4*)(gB + (size_t)row * HID + k0);
            f4 vu = *(const f4*)(uB + (size_t)row * HID + k0);
            u4v og = { f2bf(vg.x), f2bf(vg.y), f2bf(vg.z), f2bf(vg.w) };
            u4v ou = { f2bf(vu.x), f2bf(vu.y), f2bf(vu.z), f2bf(vu.w) };
            int byt = (row * 128 + bc * 8) ^ ((row & 7) << 4);
            *(u4v*)((char*)lBg + byt) = og;
            *(u4v*)((char*)lBu + byt) = ou;
        }
        __syncthreads();
        #pragma unroll
        for (int kk = 0; kk < BK; kk += 32) {
            s8v af[4], gf[4], uf[4];
            #pragma unroll
            for (int i = 0; i < 4; ++i) {
                int rowA = wm + i * 16 + lr;
                af[i] = *(const s8v*)((char*)lA + ((rowA * 128 + (kk + lk) * 2) ^ ((rowA & 7) << 4)));
                int rowB = wn + i * 16 + lr;
                int bb = (rowB * 128 + (kk + lk) * 2) ^ ((rowB & 7) << 4);
                gf[i] = *(const s8v*)((char*)lBg + bb);
                uf[i] = *(const s8v*)((char*)lBu + bb);
            }
            #pragma unroll
            for (int mi = 0; mi < 4; ++mi)
                #pragma unroll
                for (int ni = 0; ni < 4; ++ni) {
                    ag[mi][ni] = MFMA16(af[mi], gf[ni], ag[mi][ni]);
                    au[mi][ni] = MFMA16(af[mi], uf[ni], au[mi][ni]);
                }
        }
    }
    #pragma unroll
    for (int mi = 0; mi < 4; ++mi) {
        #pragma unroll
        for (int j = 0; j < 4; ++j) {
            int m = wm + mi * 16 + (lane >> 4) * 4 + j;
            if (m0 + m < M) {
                size_t rowOff = (size_t)sSlot[m] * ITR + n0 + wn + lr;
                #pragma unroll
                for (int ni = 0; ni < 4; ++ni) {
                    float g = ag[mi][ni][j], u = au[mi][ni][j];
                    float h = g * (1.f / (1.f + __expf(-g))) * u;
                    Hb[rowOff + ni * 16] = f2bf(h);
                }
            }
        }
    }
}

__global__ __launch_bounds__(256) void k_gemm2(const unsigned short* __restrict__ Hb,
                                               const float* __restrict__ Wd,
                                               const int* __restrict__ cnt,
                                               const int* __restrict__ tokL,
                                               const int* __restrict__ slotL,
                                               const float* __restrict__ gateL,
                                               float* __restrict__ out) {
    int bx = blockIdx.x;
    int e = bx / (MT1 * NT2);
    int r = bx % (MT1 * NT2);
    int mt = r / NT2, nt = r % NT2;
    int M = cnt[e];
    int m0 = mt * BM;
    if (m0 >= M) return;
    int n0 = nt * BN;

    __shared__ __align__(16) unsigned short lA[BM * BK];
    __shared__ __align__(16) unsigned short lB[BN * BK];
    __shared__ int sTok[BM];
    __shared__ int sSlot[BM];
    __shared__ float sGate[BM];

    int tid = threadIdx.x;
    if (tid < BM) {
        int m = m0 + tid;
        int mc = m < M ? m : M - 1;
        sTok[tid] = tokL[e * TT + mc];
        sSlot[tid] = slotL[e * TT + mc];
        sGate[tid] = gateL[e * TT + mc];
    }
    __syncthreads();

    int ar = tid >> 3, ac = tid & 7;
    const unsigned short* aP[4];
    #pragma unroll
    for (int i = 0; i < 4; ++i)
        aP[i] = Hb + (size_t)sSlot[ar + 32 * i] * ITR + ac * 8;

    int br = tid >> 4, bc = tid & 15;
    const float* dB = Wd + ((size_t)e * HID + n0) * ITR + bc * 4;

    int wv = tid >> 6, lane = tid & 63;
    int wm = (wv >> 1) * 64, wn = (wv & 1) * 64;
    int lr = lane & 15, lk = (lane >> 4) * 8;

    acc4 zero4 = {0.f, 0.f, 0.f, 0.f};
    acc4 a4[4][4];
    #pragma unroll
    for (int mi = 0; mi < 4; ++mi)
        #pragma unroll
        for (int ni = 0; ni < 4; ++ni) a4[mi][ni] = zero4;

    for (int k0 = 0; k0 < ITR; k0 += BK) {
        if (k0) __syncthreads();
        #pragma unroll
        for (int i = 0; i < 4; ++i) {
            int row = ar + 32 * i;
            s8v v = *(const s8v*)(aP[i] + k0);
            int byt = (row * 128 + ac * 16) ^ ((row & 7) << 4);
            *(s8v*)((char*)lA + byt) = v;
        }
        #pragma unroll
        for (int i = 0; i < 8; ++i) {
            int row = br + 16 * i;
            f4 vd = *(const f4*)(dB + (size_t)row * ITR + k0);
            u4v od = { f2bf(vd.x), f2bf(vd.y), f2bf(vd.z), f2bf(vd.w) };
            int byt = (row * 128 + bc * 8) ^ ((row & 7) << 4);
            *(u4v*)((char*)lB + byt) = od;
        }
        __syncthreads();
        #pragma unroll
        for (int kk = 0; kk < BK; kk += 32) {
            s8v af[4], bf[4];
            #pragma unroll
            for (int i = 0; i < 4; ++i) {
                int rowA = wm + i * 16 + lr;
                af[i] = *(const s8v*)((char*)lA + ((rowA * 128 + (kk + lk) * 2) ^ ((rowA & 7) << 4)));
                int rowB = wn + i * 16 + lr;
                bf[i] = *(const s8v*)((char*)lB + ((rowB * 128 + (kk + lk) * 2) ^ ((rowB & 7) << 4)));
            }
            #pragma unroll
            for (int mi = 0; mi < 4; ++mi)
                #pragma unroll
                for (int ni = 0; ni < 4; ++ni)
                    a4[mi][ni] = MFMA16(af[mi], bf[ni], a4[mi][ni]);
        }
    }
    #pragma unroll
    for (int mi = 0; mi < 4; ++mi) {
        #pragma unroll
        for (int j = 0; j < 4; ++j) {
            int m = wm + mi * 16 + (lane >> 4) * 4 + j;
            if (m0 + m < M) {
                int t = sTok[m];
                float w = sGate[m];
                float* orow = out + (size_t)t * HID + n0 + wn + lr;
                #pragma unroll
                for (int ni = 0; ni < 4; ++ni)
                    atomicAdd(orow + ni * 16, w * a4[mi][ni][j]);
            }
        }
    }
}

extern "C" void kernel_launch(void* const* d_in, const int* in_sizes, int n_in,
                              void* d_out, int out_size, void* d_ws, size_t ws_size,
                              hipStream_t stream) {
    const float* x  = (const float*)d_in[0];
    const float* rw = (const float*)d_in[1];
    const float* rb = (const float*)d_in[2];
    const float* Wg = (const float*)d_in[3];
    const float* Wu = (const float*)d_in[4];
    const float* Wd = (const float*)d_in[5];
    float* out = (float*)d_out;
    char* ws = (char*)d_ws;

    // ws layout (bytes):
    const size_t OFF_XB   = 0;                      // 32 MB
    const size_t OFF_HB   = 33554432ull;            // 176 MB
    const size_t OFF_TOK  = 218103808ull;
    const size_t OFF_SLOT = 218365952ull;
    const size_t OFF_GATE = 218628096ull;
    const size_t OFF_CNT  = 218890240ull;
    const size_t OFF_WG   = 218891264ull;           // 176 MB
    const size_t OFF_WU   = 403440640ull;           // 176 MB
    const size_t OFF_WD   = 587990016ull;           // 176 MB
    const size_t NEED     = 772539392ull;

    unsigned short* xb   = (unsigned short*)(ws + OFF_XB);
    unsigned short* Hb   = (unsigned short*)(ws + OFF_HB);
    int*   tokL  = (int*)(ws + OFF_TOK);
    int*   slotL = (int*)(ws + OFF_SLOT);
    float* gateL = (float*)(ws + OFF_GATE);
    int*   cnt   = (int*)(ws + OFF_CNT);

    hipMemsetAsync(cnt, 0, NE * sizeof(int), stream);
    hipMemsetAsync(out, 0, (size_t)out_size * sizeof(float), stream);

    if (ws_size >= NEED) {
        unsigned short* WgB = (unsigned short*)(ws + OFF_WG);
        unsigned short* WuB = (unsigned short*)(ws + OFF_WU);
        unsigned short* WdB = (unsigned short*)(ws + OFF_WD);
        k_front<<<XRT_BLOCKS + 3 * WBLK, 256, 0, stream>>>(
            x, rw, rb, xb, cnt, tokL, slotL, gateL,
            Wg, Wu, Wd, WgB, WuB, WdB);
        k_gemm1b<<<NE * MT1 * NT1, 256, 0, stream>>>(xb, WgB, WuB, cnt, tokL, slotL, Hb);
        k_gemm2b<<<NE * MT1 * NT2, 256, 0, stream>>>(Hb, WdB, cnt, tokL, slotL, gateL, out);
    } else {
        k_xrt<<<2048, 256, 0, stream>>>(x, rw, rb, xb, cnt, tokL, slotL, gateL);
        k_gemm1<<<NE * MT1 * NT1, 256, 0, stream>>>(xb, Wg, Wu, cnt, tokL, slotL, Hb);
        k_gemm2<<<NE * MT1 * NT2, 256, 0, stream>>>(Hb, Wd, cnt, tokL, slotL, gateL, out);
    }
}